// Round 2
// baseline (957.096 us; speedup 1.0000x reference)
//
#include <hip/hip_runtime.h>
#include <math.h>

#define NN 50000
#define EE 800000
#define HEADS 4
#define HIDD 64
#define OUTF 32

// ---------------- fused QKV+skip GEMM ----------------
// OUT[n, col] = sum_k X[n,k]*W[k,col] + b[col]
// blockIdx.y tile 0..3 -> Q, 4..7 -> K, 8..11 -> V, 12 -> SKIP
template<int KDIM>
__global__ __launch_bounds__(256) void qkvs_gemm(
    const float* __restrict__ X,
    const float* __restrict__ Wq, const float* __restrict__ bq,
    const float* __restrict__ Wk, const float* __restrict__ bk,
    const float* __restrict__ Wv, const float* __restrict__ bv,
    const float* __restrict__ Ws, const float* __restrict__ bs,
    float* __restrict__ Q, float* __restrict__ K,
    float* __restrict__ V, float* __restrict__ SKP)
{
    const int nt = blockIdx.y; // 0..12
    const float* W; const float* bias; float* Oout; int colbase, ostride;
    if (nt < 4)       { W = Wq; bias = bq; Oout = Q;   colbase = nt*64;     ostride = 256; }
    else if (nt < 8)  { W = Wk; bias = bk; Oout = K;   colbase = (nt-4)*64; ostride = 256; }
    else if (nt < 12) { W = Wv; bias = bv; Oout = V;   colbase = (nt-8)*64; ostride = 256; }
    else              { W = Ws; bias = bs; Oout = SKP; colbase = 0;         ostride = 64;  }
    const int wstride = ostride;

    __shared__ float sAT[32][68];   // [k][row], 68 pad keeps 16B alignment (68*4=272=16*17)
    __shared__ float sB[32][64];    // [k][col]

    const int tid = threadIdx.x;
    const int tx = tid & 15, ty = tid >> 4;
    const int row0 = blockIdx.x * 64;

    float acc[4][4] = {};

    for (int k0 = 0; k0 < KDIM; k0 += 32) {
        // A tile 64 rows x 32 k, loaded as float4, stored k-major
        #pragma unroll
        for (int i = 0; i < 2; ++i) {
            int li = tid + 256*i;          // 0..511
            int r = li >> 3, c = li & 7;   // r: row 0..63, c: float4 chunk 0..7
            int gr = row0 + r;
            float4 a4 = {0.f,0.f,0.f,0.f};
            if (gr < NN) a4 = *(const float4*)&X[(size_t)gr*KDIM + k0 + c*4];
            sAT[c*4+0][r] = a4.x; sAT[c*4+1][r] = a4.y;
            sAT[c*4+2][r] = a4.z; sAT[c*4+3][r] = a4.w;
        }
        // B tile 32 k x 64 cols, float4
        #pragma unroll
        for (int i = 0; i < 2; ++i) {
            int li = tid + 256*i;
            int kk = li >> 4, c4 = li & 15;
            *(float4*)&sB[kk][c4*4] =
                *(const float4*)&W[(size_t)(k0+kk)*wstride + colbase + c4*4];
        }
        __syncthreads();
        #pragma unroll
        for (int kk = 0; kk < 32; ++kk) {
            float4 a4 = *(const float4*)&sAT[kk][ty*4];   // ds_read_b128
            float4 b4 = *(const float4*)&sB[kk][tx*4];    // ds_read_b128
            float a[4] = {a4.x, a4.y, a4.z, a4.w};
            float b[4] = {b4.x, b4.y, b4.z, b4.w};
            #pragma unroll
            for (int i = 0; i < 4; ++i)
                #pragma unroll
                for (int j = 0; j < 4; ++j)
                    acc[i][j] += a[i]*b[j];
        }
        __syncthreads();
    }
    #pragma unroll
    for (int i = 0; i < 4; ++i) {
        int gr = row0 + ty*4 + i;
        if (gr >= NN) continue;
        #pragma unroll
        for (int j = 0; j < 4; ++j) {
            int c = colbase + tx*4 + j;
            Oout[(size_t)gr*ostride + c] = acc[i][j] + bias[c];
        }
    }
}

// ---------------- CSR build (dst-bucketed), reused by both layers ----------------
__global__ __launch_bounds__(256) void hist_kernel(const int* __restrict__ dstA,
                                                   int* __restrict__ deg)
{
    int e = blockIdx.x * 256 + threadIdx.x;   // EE divisible by 256
    atomicAdd(&deg[dstA[e]], 1);
}

__global__ __launch_bounds__(1024) void scan_kernel(const int* __restrict__ deg,
                                                    int* __restrict__ rowptr,
                                                    int* __restrict__ cursor)
{
    __shared__ int sdata[1024];
    __shared__ int soff;
    const int tid = threadIdx.x;
    if (tid == 0) soff = 0;
    __syncthreads();
    for (int base = 0; base < NN; base += 1024) {
        int v = (base + tid < NN) ? deg[base + tid] : 0;
        sdata[tid] = v;
        __syncthreads();
        #pragma unroll
        for (int off = 1; off < 1024; off <<= 1) {
            int t = (tid >= off) ? sdata[tid - off] : 0;
            __syncthreads();
            sdata[tid] += t;
            __syncthreads();
        }
        int excl = sdata[tid] - v;
        if (base + tid < NN) {
            rowptr[base + tid] = soff + excl;
            cursor[base + tid] = soff + excl;
        }
        int total = sdata[1023];
        __syncthreads();
        if (tid == 0) soff += total;
        __syncthreads();
    }
    if (tid == 0) rowptr[NN] = EE;
}

__global__ __launch_bounds__(256) void scatter_kernel(const int* __restrict__ srcA,
                                                      const int* __restrict__ dstA,
                                                      int* __restrict__ cursor,
                                                      int* __restrict__ colidx)
{
    int e = blockIdx.x * 256 + threadIdx.x;
    int p = atomicAdd(&cursor[dstA[e]], 1);
    colidx[p] = srcA[e];
}

// ---------------- fused node-centric attention + head-mean + skip + LN ----------------
// one wave per node; lane: h = lane>>4 (head), t = lane&15 (float4 chunk of 64 dims)
template<bool RELU>
__global__ __launch_bounds__(256) void node_attn(
    const int* __restrict__ rowptr, const int* __restrict__ colidx,
    const float* __restrict__ Q, const float* __restrict__ K,
    const float* __restrict__ V, const float* __restrict__ SKP,
    const float* __restrict__ g, const float* __restrict__ b,
    float* __restrict__ Hout)
{
    int n = (blockIdx.x * blockDim.x + threadIdx.x) >> 6;
    if (n >= NN) return;
    const int lane = threadIdx.x & 63;
    const int h = lane >> 4, t = lane & 15;

    const float4 q4 = *(const float4*)&Q[(size_t)n*256 + h*64 + t*4];

    float4 acc = {0.f,0.f,0.f,0.f};
    float ssum = 0.f;
    const int e0 = rowptr[n], e1 = rowptr[n+1];
    for (int e = e0; e < e1; ++e) {
        const int s = colidx[e];
        const float4 k4 = *(const float4*)&K[(size_t)s*256 + h*64 + t*4];
        float p = q4.x*k4.x + q4.y*k4.y + q4.z*k4.z + q4.w*k4.w;
        p += __shfl_xor(p, 1);
        p += __shfl_xor(p, 2);
        p += __shfl_xor(p, 4);
        p += __shfl_xor(p, 8);                 // full 64-dim dot in all 16 lanes of head group
        const float eh = expf(p * 0.125f);     // 1/sqrt(64)
        const float4 v4 = *(const float4*)&V[(size_t)s*256 + h*64 + t*4];
        ssum  += eh;
        acc.x += eh*v4.x; acc.y += eh*v4.y; acc.z += eh*v4.z; acc.w += eh*v4.w;
    }
    const float inv = (ssum != 0.f) ? 1.f/ssum : 0.f;   // empty-segment guard (ref -> 0)
    acc.x *= inv; acc.y *= inv; acc.z *= inv; acc.w *= inv;

    // mean over heads: lanes {t, t+16, t+32, t+48} hold the same dims for h=0..3
    #pragma unroll
    for (int o = 16; o < 64; o <<= 1) {
        acc.x += __shfl_xor(acc.x, o); acc.y += __shfl_xor(acc.y, o);
        acc.z += __shfl_xor(acc.z, o); acc.w += __shfl_xor(acc.w, o);
    }
    const float4 sk4 = *(const float4*)&SKP[(size_t)n*64 + t*4];
    float4 val;
    val.x = acc.x*0.25f + sk4.x; val.y = acc.y*0.25f + sk4.y;
    val.z = acc.z*0.25f + sk4.z; val.w = acc.w*0.25f + sk4.w;

    // LayerNorm over 64 dims (each 16-lane group holds all 64, duplicated across h)
    float m  = val.x + val.y + val.z + val.w;
    float m2 = val.x*val.x + val.y*val.y + val.z*val.z + val.w*val.w;
    #pragma unroll
    for (int o = 1; o < 16; o <<= 1) { m += __shfl_xor(m, o); m2 += __shfl_xor(m2, o); }
    m *= (1.f/64.f); m2 *= (1.f/64.f);
    const float rstd = rsqrtf(m2 - m*m + 1e-5f);
    const float4 g4 = *(const float4*)&g[t*4];
    const float4 b4 = *(const float4*)&b[t*4];
    float4 y;
    y.x = (val.x - m)*rstd*g4.x + b4.x;
    y.y = (val.y - m)*rstd*g4.y + b4.y;
    y.z = (val.z - m)*rstd*g4.z + b4.z;
    y.w = (val.w - m)*rstd*g4.w + b4.w;
    if (RELU) {
        y.x = fmaxf(y.x, 0.f); y.y = fmaxf(y.y, 0.f);
        y.z = fmaxf(y.z, 0.f); y.w = fmaxf(y.w, 0.f);
    }
    if (h == 0) *(float4*)&Hout[(size_t)n*64 + t*4] = y;
}

// ---------------- final 64->32 linear ----------------
__global__ __launch_bounds__(256) void final_gemm(
    const float* __restrict__ H, const float* __restrict__ Wf,
    const float* __restrict__ bf, float* __restrict__ out)
{
    __shared__ float sW[64][32];
    __shared__ float sH[8][64];
    const int tid = threadIdx.x;
    #pragma unroll
    for (int i = 0; i < 8; ++i) {
        int li = tid + 256*i;
        sW[li >> 5][li & 31] = Wf[li];
    }
    const int n0 = blockIdx.x * 8;
    #pragma unroll
    for (int i = 0; i < 2; ++i) {
        int li = tid + 256*i;
        int r = li >> 6, d = li & 63;
        int gn = n0 + r;
        sH[r][d] = (gn < NN) ? H[(size_t)gn*64 + d] : 0.f;
    }
    __syncthreads();
    const int o = tid & 31, nl = tid >> 5;
    const int gn = n0 + nl;
    if (gn >= NN) return;
    float acc = bf[o];
    #pragma unroll
    for (int dd = 0; dd < 64; ++dd) acc += sH[nl][dd] * sW[dd][o];
    out[(size_t)gn*32 + o] = acc;
}

extern "C" void kernel_launch(void* const* d_in, const int* in_sizes, int n_in,
                              void* d_out, int out_size, void* d_ws, size_t ws_size,
                              hipStream_t stream) {
    const float* x   = (const float*)d_in[0];
    const int*   ei  = (const int*)d_in[1];
    const int* srcA = ei;
    const int* dstA = ei + EE;
    const float *Wq1=(const float*)d_in[2],  *bq1=(const float*)d_in[3];
    const float *Wk1=(const float*)d_in[4],  *bk1=(const float*)d_in[5];
    const float *Wv1=(const float*)d_in[6],  *bv1=(const float*)d_in[7];
    const float *Ws1=(const float*)d_in[8],  *bs1=(const float*)d_in[9];
    const float *Wq2=(const float*)d_in[10], *bq2=(const float*)d_in[11];
    const float *Wk2=(const float*)d_in[12], *bk2=(const float*)d_in[13];
    const float *Wv2=(const float*)d_in[14], *bv2=(const float*)d_in[15];
    const float *Ws2=(const float*)d_in[16], *bs2=(const float*)d_in[17];
    const float *ln_g=(const float*)d_in[18],*ln_b=(const float*)d_in[19];
    const float *Wf=(const float*)d_in[20],  *bf=(const float*)d_in[21];
    float* out = (float*)d_out;

    float* ws = (float*)d_ws;
    size_t off = 0;
    float* Q   = ws + off; off += (size_t)NN*256;
    float* Kb  = ws + off; off += (size_t)NN*256;
    float* Vb  = ws + off; off += (size_t)NN*256;
    float* SKP = ws + off; off += (size_t)NN*64;
    float* H1  = ws + off; off += (size_t)NN*64;
    float* H2  = ws + off; off += (size_t)NN*64;
    int* deg    = (int*)(ws + off); off += NN;
    int* rowptr = (int*)(ws + off); off += NN + 1;
    int* cursor = (int*)(ws + off); off += NN;
    int* colidx = (int*)(ws + off); off += EE;

    const dim3 gemmGrid((NN + 63) / 64, 13);
    const int edgeBlocks = EE / 256;            // exact: 3125
    const int nodeBlocks = NN / 4;              // exact: 12500, 4 waves/block

    // ---- CSR build (dst-bucketed), used by both layers ----
    hipMemsetAsync(deg, 0, NN * sizeof(int), stream);
    hist_kernel<<<edgeBlocks, 256, 0, stream>>>(dstA, deg);
    scan_kernel<<<1, 1024, 0, stream>>>(deg, rowptr, cursor);
    scatter_kernel<<<edgeBlocks, 256, 0, stream>>>(srcA, dstA, cursor, colidx);

    // ---- layer 1 ----
    qkvs_gemm<128><<<gemmGrid, 256, 0, stream>>>(x, Wq1,bq1, Wk1,bk1, Wv1,bv1, Ws1,bs1,
                                                 Q, Kb, Vb, SKP);
    node_attn<true><<<nodeBlocks, 256, 0, stream>>>(rowptr, colidx, Q, Kb, Vb, SKP,
                                                    ln_g, ln_b, H1);

    // ---- layer 2 ----
    qkvs_gemm<64><<<gemmGrid, 256, 0, stream>>>(H1, Wq2,bq2, Wk2,bk2, Wv2,bv2, Ws2,bs2,
                                                Q, Kb, Vb, SKP);
    node_attn<false><<<nodeBlocks, 256, 0, stream>>>(rowptr, colidx, Q, Kb, Vb, SKP,
                                                     ln_g, ln_b, H2);

    // ---- final linear ----
    final_gemm<<<NN / 8, 256, 0, stream>>>(H2, Wf, bf, out);
}

// Round 6
// 753.890 us; speedup vs baseline: 1.2695x; 1.2695x over previous
//
#include <hip/hip_runtime.h>
#include <hip/hip_fp16.h>
#include <math.h>

#define NN 50000
#define EE 800000
#define HEADS 4
#define HIDD 64
#define OUTF 32

struct __align__(8) h4v { __half2 a, b; };

// ---------------- fused QKV+skip GEMM ----------------
// grid = (13, rowTiles): blockIdx.x = weight tile (x fastest in dispatch order,
// so the 13 tiles sharing one X row-strip run back-to-back -> L2/LLC locality).
// tiles 0..3 -> Q (fp32), 4..7 -> K (fp16, KV[.. 0..255]), 8..11 -> V (fp16,
// KV[.. 256..511]), 12 -> SKIP (fp32)
template<int KDIM>
__global__ __launch_bounds__(256) void qkvs_gemm(
    const float* __restrict__ X,
    const float* __restrict__ Wq, const float* __restrict__ bq,
    const float* __restrict__ Wk, const float* __restrict__ bk,
    const float* __restrict__ Wv, const float* __restrict__ bv,
    const float* __restrict__ Ws, const float* __restrict__ bs,
    float* __restrict__ Q, __half* __restrict__ KV, float* __restrict__ SKP)
{
    const int nt = blockIdx.x; // 0..12
    const float* W; const float* bias; int mode, bcol, wstride;
    if (nt < 4)       { W = Wq; bias = bq; mode = 0; bcol = nt*64;     wstride = 256; }
    else if (nt < 8)  { W = Wk; bias = bk; mode = 1; bcol = (nt-4)*64; wstride = 256; }
    else if (nt < 12) { W = Wv; bias = bv; mode = 2; bcol = (nt-8)*64; wstride = 256; }
    else              { W = Ws; bias = bs; mode = 3; bcol = 0;         wstride = 64;  }

    __shared__ float sAT[32][68];   // [k][row], 68 pad keeps 16B alignment
    __shared__ float sB[32][64];    // [k][col]

    const int tid = threadIdx.x;
    const int tx = tid & 15, ty = tid >> 4;
    const int row0 = blockIdx.y * 64;

    float acc[4][4] = {};

    for (int k0 = 0; k0 < KDIM; k0 += 32) {
        #pragma unroll
        for (int i = 0; i < 2; ++i) {
            int li = tid + 256*i;          // 0..511
            int r = li >> 3, c = li & 7;   // row 0..63, float4 chunk 0..7
            int gr = row0 + r;
            float4 a4 = {0.f,0.f,0.f,0.f};
            if (gr < NN) a4 = *(const float4*)&X[(size_t)gr*KDIM + k0 + c*4];
            sAT[c*4+0][r] = a4.x; sAT[c*4+1][r] = a4.y;
            sAT[c*4+2][r] = a4.z; sAT[c*4+3][r] = a4.w;
        }
        #pragma unroll
        for (int i = 0; i < 2; ++i) {
            int li = tid + 256*i;
            int kk = li >> 4, c4 = li & 15;
            *(float4*)&sB[kk][c4*4] =
                *(const float4*)&W[(size_t)(k0+kk)*wstride + bcol + c4*4];
        }
        __syncthreads();
        #pragma unroll
        for (int kk = 0; kk < 32; ++kk) {
            float4 a4 = *(const float4*)&sAT[kk][ty*4];   // ds_read_b128
            float4 b4 = *(const float4*)&sB[kk][tx*4];    // ds_read_b128
            float a[4] = {a4.x, a4.y, a4.z, a4.w};
            float b[4] = {b4.x, b4.y, b4.z, b4.w};
            #pragma unroll
            for (int i = 0; i < 4; ++i)
                #pragma unroll
                for (int j = 0; j < 4; ++j)
                    acc[i][j] += a[i]*b[j];
        }
        __syncthreads();
    }
    #pragma unroll
    for (int i = 0; i < 4; ++i) {
        int gr = row0 + ty*4 + i;
        if (gr >= NN) continue;
        float o[4];
        #pragma unroll
        for (int j = 0; j < 4; ++j) o[j] = acc[i][j] + bias[bcol + tx*4 + j];
        if (mode == 0) {
            *(float4*)&Q[(size_t)gr*256 + bcol + tx*4] = {o[0],o[1],o[2],o[3]};
        } else if (mode == 3) {
            *(float4*)&SKP[(size_t)gr*64 + tx*4] = {o[0],o[1],o[2],o[3]};
        } else {
            h4v hh;
            hh.a = __floats2half2_rn(o[0], o[1]);
            hh.b = __floats2half2_rn(o[2], o[3]);
            size_t base = (size_t)gr*512 + (mode == 2 ? 256 : 0) + bcol + tx*4;
            *(h4v*)&KV[base] = hh;
        }
    }
}

// ---------------- CSR build (dst-bucketed), reused by both layers ----------------
__global__ __launch_bounds__(256) void hist_kernel(const int* __restrict__ dstA,
                                                   int* __restrict__ deg)
{
    int e = blockIdx.x * 256 + threadIdx.x;   // EE divisible by 256
    atomicAdd(&deg[dstA[e]], 1);
}

__global__ __launch_bounds__(1024) void scan_kernel(const int* __restrict__ deg,
                                                    int* __restrict__ rowptr,
                                                    int* __restrict__ cursor)
{
    __shared__ int sdata[1024];
    __shared__ int soff;
    const int tid = threadIdx.x;
    if (tid == 0) soff = 0;
    __syncthreads();
    for (int base = 0; base < NN; base += 1024) {
        int v = (base + tid < NN) ? deg[base + tid] : 0;
        sdata[tid] = v;
        __syncthreads();
        #pragma unroll
        for (int off = 1; off < 1024; off <<= 1) {
            int t = (tid >= off) ? sdata[tid - off] : 0;
            __syncthreads();
            sdata[tid] += t;
            __syncthreads();
        }
        int excl = sdata[tid] - v;
        if (base + tid < NN) {
            rowptr[base + tid] = soff + excl;
            cursor[base + tid] = soff + excl;
        }
        int total = sdata[1023];
        __syncthreads();
        if (tid == 0) soff += total;
        __syncthreads();
    }
    if (tid == 0) rowptr[NN] = EE;
}

__global__ __launch_bounds__(256) void scatter_kernel(const int* __restrict__ srcA,
                                                      const int* __restrict__ dstA,
                                                      int* __restrict__ cursor,
                                                      int* __restrict__ colidx)
{
    int e = blockIdx.x * 256 + threadIdx.x;
    int p = atomicAdd(&cursor[dstA[e]], 1);
    colidx[p] = srcA[e];
}

// ---------------- fused node-centric attention + head-mean + skip + LN ----------------
// one wave per node; lane: h = lane>>4 (head), t = lane&15 (float4 chunk of 64 dims)
template<bool RELU>
__global__ __launch_bounds__(256) void node_attn(
    const int* __restrict__ rowptr, const int* __restrict__ colidx,
    const float* __restrict__ Q, const __half* __restrict__ KV,
    const float* __restrict__ SKP,
    const float* __restrict__ g, const float* __restrict__ b,
    float* __restrict__ Hout)
{
    int n = (blockIdx.x * blockDim.x + threadIdx.x) >> 6;
    if (n >= NN) return;
    const int lane = threadIdx.x & 63;
    const int h = lane >> 4, t = lane & 15;
    const int hoff = h*64 + t*4;

    const float4 q4 = *(const float4*)&Q[(size_t)n*256 + hoff];

    float4 acc = {0.f,0.f,0.f,0.f};
    float ssum = 0.f;
    const int e0 = rowptr[n], e1 = rowptr[n+1];
    int e = e0;
    for (; e + 2 <= e1; e += 2) {               // unrolled x2 for MLP
        const int s0 = colidx[e], s1 = colidx[e+1];
        const size_t b0 = (size_t)s0*512 + hoff;
        const size_t b1 = (size_t)s1*512 + hoff;
        const h4v kh0 = *(const h4v*)&KV[b0];
        const h4v kh1 = *(const h4v*)&KV[b1];
        const h4v vh0 = *(const h4v*)&KV[b0 + 256];
        const h4v vh1 = *(const h4v*)&KV[b1 + 256];
        const float2 k0a = __half22float2(kh0.a), k0b = __half22float2(kh0.b);
        const float2 k1a = __half22float2(kh1.a), k1b = __half22float2(kh1.b);
        float p0 = q4.x*k0a.x + q4.y*k0a.y + q4.z*k0b.x + q4.w*k0b.y;
        float p1 = q4.x*k1a.x + q4.y*k1a.y + q4.z*k1b.x + q4.w*k1b.y;
        p0 += __shfl_xor(p0, 1);  p1 += __shfl_xor(p1, 1);
        p0 += __shfl_xor(p0, 2);  p1 += __shfl_xor(p1, 2);
        p0 += __shfl_xor(p0, 4);  p1 += __shfl_xor(p1, 4);
        p0 += __shfl_xor(p0, 8);  p1 += __shfl_xor(p1, 8);
        const float eh0 = expf(p0 * 0.125f);
        const float eh1 = expf(p1 * 0.125f);
        const float2 v0a = __half22float2(vh0.a), v0b = __half22float2(vh0.b);
        const float2 v1a = __half22float2(vh1.a), v1b = __half22float2(vh1.b);
        ssum  += eh0 + eh1;
        acc.x += eh0*v0a.x + eh1*v1a.x;
        acc.y += eh0*v0a.y + eh1*v1a.y;
        acc.z += eh0*v0b.x + eh1*v1b.x;
        acc.w += eh0*v0b.y + eh1*v1b.y;
    }
    for (; e < e1; ++e) {
        const int s = colidx[e];
        const size_t b0 = (size_t)s*512 + hoff;
        const h4v kh = *(const h4v*)&KV[b0];
        const h4v vh = *(const h4v*)&KV[b0 + 256];
        const float2 ka = __half22float2(kh.a), kb = __half22float2(kh.b);
        float p = q4.x*ka.x + q4.y*ka.y + q4.z*kb.x + q4.w*kb.y;
        p += __shfl_xor(p, 1);
        p += __shfl_xor(p, 2);
        p += __shfl_xor(p, 4);
        p += __shfl_xor(p, 8);
        const float eh = expf(p * 0.125f);
        const float2 va = __half22float2(vh.a), vb = __half22float2(vh.b);
        ssum  += eh;
        acc.x += eh*va.x; acc.y += eh*va.y; acc.z += eh*vb.x; acc.w += eh*vb.y;
    }
    const float inv = (ssum != 0.f) ? 1.f/ssum : 0.f;   // empty-segment guard
    acc.x *= inv; acc.y *= inv; acc.z *= inv; acc.w *= inv;

    // mean over heads: lanes {t, t+16, t+32, t+48} hold the same dims
    #pragma unroll
    for (int o = 16; o < 64; o <<= 1) {
        acc.x += __shfl_xor(acc.x, o); acc.y += __shfl_xor(acc.y, o);
        acc.z += __shfl_xor(acc.z, o); acc.w += __shfl_xor(acc.w, o);
    }
    const float4 sk4 = *(const float4*)&SKP[(size_t)n*64 + t*4];
    float4 val;
    val.x = acc.x*0.25f + sk4.x; val.y = acc.y*0.25f + sk4.y;
    val.z = acc.z*0.25f + sk4.z; val.w = acc.w*0.25f + sk4.w;

    // LayerNorm over 64 dims (each 16-lane group holds all 64)
    float m  = val.x + val.y + val.z + val.w;
    float m2 = val.x*val.x + val.y*val.y + val.z*val.z + val.w*val.w;
    #pragma unroll
    for (int o = 1; o < 16; o <<= 1) { m += __shfl_xor(m, o); m2 += __shfl_xor(m2, o); }
    m *= (1.f/64.f); m2 *= (1.f/64.f);
    const float rstd = rsqrtf(m2 - m*m + 1e-5f);
    const float4 g4 = *(const float4*)&g[t*4];
    const float4 b4 = *(const float4*)&b[t*4];
    float4 y;
    y.x = (val.x - m)*rstd*g4.x + b4.x;
    y.y = (val.y - m)*rstd*g4.y + b4.y;
    y.z = (val.z - m)*rstd*g4.z + b4.z;
    y.w = (val.w - m)*rstd*g4.w + b4.w;
    if (RELU) {
        y.x = fmaxf(y.x, 0.f); y.y = fmaxf(y.y, 0.f);
        y.z = fmaxf(y.z, 0.f); y.w = fmaxf(y.w, 0.f);
    }
    if (h == 0) *(float4*)&Hout[(size_t)n*64 + t*4] = y;
}

// ---------------- final 64->32 linear ----------------
__global__ __launch_bounds__(256) void final_gemm(
    const float* __restrict__ H, const float* __restrict__ Wf,
    const float* __restrict__ bf, float* __restrict__ out)
{
    __shared__ float sW[64][32];
    __shared__ float sH[8][64];
    const int tid = threadIdx.x;
    #pragma unroll
    for (int i = 0; i < 8; ++i) {
        int li = tid + 256*i;
        sW[li >> 5][li & 31] = Wf[li];
    }
    const int n0 = blockIdx.x * 8;
    #pragma unroll
    for (int i = 0; i < 2; ++i) {
        int li = tid + 256*i;
        int r = li >> 6, d = li & 63;
        int gn = n0 + r;
        sH[r][d] = (gn < NN) ? H[(size_t)gn*64 + d] : 0.f;
    }
    __syncthreads();
    const int o = tid & 31, nl = tid >> 5;
    const int gn = n0 + nl;
    if (gn >= NN) return;
    float acc = bf[o];
    #pragma unroll
    for (int dd = 0; dd < 64; ++dd) acc += sH[nl][dd] * sW[dd][o];
    out[(size_t)gn*32 + o] = acc;
}

extern "C" void kernel_launch(void* const* d_in, const int* in_sizes, int n_in,
                              void* d_out, int out_size, void* d_ws, size_t ws_size,
                              hipStream_t stream) {
    const float* x   = (const float*)d_in[0];
    const int*   ei  = (const int*)d_in[1];
    const int* srcA = ei;
    const int* dstA = ei + EE;
    const float *Wq1=(const float*)d_in[2],  *bq1=(const float*)d_in[3];
    const float *Wk1=(const float*)d_in[4],  *bk1=(const float*)d_in[5];
    const float *Wv1=(const float*)d_in[6],  *bv1=(const float*)d_in[7];
    const float *Ws1=(const float*)d_in[8],  *bs1=(const float*)d_in[9];
    const float *Wq2=(const float*)d_in[10], *bq2=(const float*)d_in[11];
    const float *Wk2=(const float*)d_in[12], *bk2=(const float*)d_in[13];
    const float *Wv2=(const float*)d_in[14], *bv2=(const float*)d_in[15];
    const float *Ws2=(const float*)d_in[16], *bs2=(const float*)d_in[17];
    const float *ln_g=(const float*)d_in[18],*ln_b=(const float*)d_in[19];
    const float *Wf=(const float*)d_in[20],  *bf=(const float*)d_in[21];
    float* out = (float*)d_out;

    float* ws = (float*)d_ws;
    size_t off = 0;
    float* Q    = ws + off; off += (size_t)NN*256;
    __half* KV  = (__half*)(ws + off); off += (size_t)NN*256;  // NN*512 halves
    float* SKP  = ws + off; off += (size_t)NN*64;
    float* H1   = ws + off; off += (size_t)NN*64;
    float* H2   = ws + off; off += (size_t)NN*64;
    int* deg    = (int*)(ws + off); off += NN;
    int* rowptr = (int*)(ws + off); off += NN + 1;
    int* cursor = (int*)(ws + off); off += NN;
    int* colidx = (int*)(ws + off); off += EE;

    const dim3 gemmGrid(13, (NN + 63) / 64);
    const int edgeBlocks = EE / 256;            // 3125
    const int nodeBlocks = NN / 4;              // 12500, 4 waves/block

    // ---- CSR build (dst-bucketed), used by both layers ----
    hipMemsetAsync(deg, 0, NN * sizeof(int), stream);
    hist_kernel<<<edgeBlocks, 256, 0, stream>>>(dstA, deg);
    scan_kernel<<<1, 1024, 0, stream>>>(deg, rowptr, cursor);
    scatter_kernel<<<edgeBlocks, 256, 0, stream>>>(srcA, dstA, cursor, colidx);

    // ---- layer 1 ----
    qkvs_gemm<128><<<gemmGrid, 256, 0, stream>>>(x, Wq1,bq1, Wk1,bk1, Wv1,bv1, Ws1,bs1,
                                                 Q, KV, SKP);
    node_attn<true><<<nodeBlocks, 256, 0, stream>>>(rowptr, colidx, Q, KV, SKP,
                                                    ln_g, ln_b, H1);

    // ---- layer 2 ----
    qkvs_gemm<64><<<gemmGrid, 256, 0, stream>>>(H1, Wq2,bq2, Wk2,bk2, Wv2,bv2, Ws2,bs2,
                                                Q, KV, SKP);
    node_attn<false><<<nodeBlocks, 256, 0, stream>>>(rowptr, colidx, Q, KV, SKP,
                                                     ln_g, ln_b, H2);

    // ---- final linear ----
    final_gemm<<<NN / 8, 256, 0, stream>>>(H2, Wf, bf, out);
}

// Round 8
// 743.154 us; speedup vs baseline: 1.2879x; 1.0144x over previous
//
#include <hip/hip_runtime.h>
#include <hip/hip_fp16.h>
#include <math.h>

#define NN 50000
#define EE 800000
#define HEADS 4
#define HIDD 64
#define OUTF 32
#define NXCD 8

struct __align__(8)  h4v { __half2 a, b; };
struct __align__(16) h8v { __half2 a, b, c, d; };   // 4 K-halves + 4 V-halves

// ---------------- fused QKV+skip GEMM ----------------
// 1D grid of 13*ceil(NN/128) blocks. Work w remapped bijectively so each XCD
// gets a CONTIGUOUS chunk of work (m204): the 13 weight tiles sharing one
// 128-row X strip run back-to-back on the SAME XCD -> strip stays in that
// XCD's L2; W (425 KB total) is L2-resident per XCD.
// Tile: 128 rows x 64 cols, 256 threads, 8x4 acc/thread, K-tile 32.
// tiles 0..3 -> Q (fp32), 4..7 -> K, 8..11 -> V (fp16 interleaved KV), 12 -> SKIP
template<int KDIM>
__global__ __launch_bounds__(256) void qkvs_gemm(
    const float* __restrict__ X,
    const float* __restrict__ Wq, const float* __restrict__ bq,
    const float* __restrict__ Wk, const float* __restrict__ bk,
    const float* __restrict__ Wv, const float* __restrict__ bv,
    const float* __restrict__ Ws, const float* __restrict__ bs,
    float* __restrict__ Q, __half* __restrict__ KV, float* __restrict__ SKP)
{
    // bijective XCD remap (consecutive blockIdx -> round-robin XCD on MI355X)
    const int nwg = gridDim.x;
    const int i   = blockIdx.x;
    const int q8  = nwg >> 3, r8 = nwg & 7;
    const int xcd = i & 7, j = i >> 3;
    const int w   = (xcd < r8 ? xcd * (q8 + 1) : r8 * (q8 + 1) + (xcd - r8) * q8) + j;

    const int nt   = w % 13;        // weight tile
    const int row0 = (w / 13) * 128;

    const float* W; const float* bias; int mode, bcol, wstride;
    if (nt < 4)       { W = Wq; bias = bq; mode = 0; bcol = nt*64;     wstride = 256; }
    else if (nt < 8)  { W = Wk; bias = bk; mode = 1; bcol = (nt-4)*64; wstride = 256; }
    else if (nt < 12) { W = Wv; bias = bv; mode = 2; bcol = (nt-8)*64; wstride = 256; }
    else              { W = Ws; bias = bs; mode = 3; bcol = 0;         wstride = 64;  }

    __shared__ float sAT[32][132];  // [k][row], 132 pad: 528B rows, 16B-aligned
    __shared__ float sB[32][64];    // [k][col]

    const int tid = threadIdx.x;
    const int tx = tid & 15, ty = tid >> 4;   // cols tx*4..+3, rows ty*8..+7

    float acc[8][4] = {};

    for (int k0 = 0; k0 < KDIM; k0 += 32) {
        // A tile 128 rows x 32 k, float4 global loads, stored k-major
        #pragma unroll
        for (int it = 0; it < 4; ++it) {
            int li = tid + 256*it;         // 0..1023
            int r = li >> 3, c = li & 7;   // row 0..127, float4 chunk 0..7
            int gr = row0 + r;
            float4 a4 = {0.f,0.f,0.f,0.f};
            if (gr < NN) a4 = *(const float4*)&X[(size_t)gr*KDIM + k0 + c*4];
            sAT[c*4+0][r] = a4.x; sAT[c*4+1][r] = a4.y;
            sAT[c*4+2][r] = a4.z; sAT[c*4+3][r] = a4.w;
        }
        // B tile 32 k x 64 cols
        #pragma unroll
        for (int it = 0; it < 2; ++it) {
            int li = tid + 256*it;
            int kk = li >> 4, c4 = li & 15;
            *(float4*)&sB[kk][c4*4] =
                *(const float4*)&W[(size_t)(k0+kk)*wstride + bcol + c4*4];
        }
        __syncthreads();
        #pragma unroll
        for (int kk = 0; kk < 32; ++kk) {
            float4 a0 = *(const float4*)&sAT[kk][ty*8];      // ds_read_b128
            float4 a1 = *(const float4*)&sAT[kk][ty*8+4];    // ds_read_b128
            float4 b4 = *(const float4*)&sB[kk][tx*4];       // ds_read_b128
            float a[8] = {a0.x,a0.y,a0.z,a0.w, a1.x,a1.y,a1.z,a1.w};
            float b[4] = {b4.x,b4.y,b4.z,b4.w};
            #pragma unroll
            for (int ii = 0; ii < 8; ++ii)
                #pragma unroll
                for (int jj = 0; jj < 4; ++jj)
                    acc[ii][jj] += a[ii]*b[jj];
        }
        __syncthreads();
    }

    const float4 bia = *(const float4*)&bias[bcol + tx*4];
    #pragma unroll
    for (int ii = 0; ii < 8; ++ii) {
        int gr = row0 + ty*8 + ii;
        if (gr >= NN) continue;
        float o0 = acc[ii][0] + bia.x, o1 = acc[ii][1] + bia.y;
        float o2 = acc[ii][2] + bia.z, o3 = acc[ii][3] + bia.w;
        if (mode == 0) {
            *(float4*)&Q[(size_t)gr*256 + bcol + tx*4] = {o0,o1,o2,o3};
        } else if (mode == 3) {
            *(float4*)&SKP[(size_t)gr*64 + tx*4] = {o0,o1,o2,o3};
        } else {
            // interleaved: KV[n][h][t][0:4]=K-chunk, [4:8]=V-chunk (halves)
            h4v hh;
            hh.a = __floats2half2_rn(o0, o1);
            hh.b = __floats2half2_rn(o2, o3);
            int h = (mode == 1) ? nt-4 : nt-8;
            size_t base = (size_t)gr*512 + h*128 + tx*8 + (mode == 2 ? 4 : 0);
            *(h4v*)&KV[base] = hh;
        }
    }
}

// ---------------- CSR build (dst-bucketed), reused by both layers ----------------
__global__ __launch_bounds__(256) void hist_kernel(const int* __restrict__ dstA,
                                                   int* __restrict__ deg)
{
    int e = blockIdx.x * 256 + threadIdx.x;   // EE divisible by 256
    atomicAdd(&deg[dstA[e]], 1);
}

__global__ __launch_bounds__(1024) void scan_kernel(const int* __restrict__ deg,
                                                    int* __restrict__ rowptr,
                                                    int* __restrict__ cursor)
{
    __shared__ int sdata[1024];
    __shared__ int soff;
    const int tid = threadIdx.x;
    if (tid == 0) soff = 0;
    __syncthreads();
    for (int base = 0; base < NN; base += 1024) {
        int v = (base + tid < NN) ? deg[base + tid] : 0;
        sdata[tid] = v;
        __syncthreads();
        #pragma unroll
        for (int off = 1; off < 1024; off <<= 1) {
            int t = (tid >= off) ? sdata[tid - off] : 0;
            __syncthreads();
            sdata[tid] += t;
            __syncthreads();
        }
        int excl = sdata[tid] - v;
        if (base + tid < NN) {
            rowptr[base + tid] = soff + excl;
            cursor[base + tid] = soff + excl;
        }
        int total = sdata[1023];
        __syncthreads();
        if (tid == 0) soff += total;
        __syncthreads();
    }
    if (tid == 0) rowptr[NN] = EE;
}

__global__ __launch_bounds__(256) void scatter_kernel(const int* __restrict__ srcA,
                                                      const int* __restrict__ dstA,
                                                      int* __restrict__ cursor,
                                                      int* __restrict__ colidx)
{
    int e = blockIdx.x * 256 + threadIdx.x;
    int p = atomicAdd(&cursor[dstA[e]], 1);
    colidx[p] = srcA[e];
}

// ---------------- fused node-centric attention + head-mean + skip + LN ----------------
// one wave per node; lane: h = lane>>4 (head), t = lane&15.
// ONE 16B load per edge per lane (K-chunk + V-chunk interleaved).
template<bool RELU>
__global__ __launch_bounds__(256) void node_attn(
    const int* __restrict__ rowptr, const int* __restrict__ colidx,
    const float* __restrict__ Q, const __half* __restrict__ KV,
    const float* __restrict__ SKP,
    const float* __restrict__ g, const float* __restrict__ b,
    float* __restrict__ Hout)
{
    int n = (blockIdx.x * blockDim.x + threadIdx.x) >> 6;
    if (n >= NN) return;
    const int lane = threadIdx.x & 63;
    const int h = lane >> 4, t = lane & 15;
    const int kvoff = h*128 + t*8;

    const float4 q4 = *(const float4*)&Q[(size_t)n*256 + h*64 + t*4];

    float4 acc = {0.f,0.f,0.f,0.f};
    float ssum = 0.f;
    const int e0 = rowptr[n], e1 = rowptr[n+1];
    int e = e0;
    for (; e + 2 <= e1; e += 2) {
        const int s0 = colidx[e], s1 = colidx[e+1];
        const h8v kv0 = *(const h8v*)&KV[(size_t)s0*512 + kvoff];
        const h8v kv1 = *(const h8v*)&KV[(size_t)s1*512 + kvoff];
        const float2 k0a = __half22float2(kv0.a), k0b = __half22float2(kv0.b);
        const float2 k1a = __half22float2(kv1.a), k1b = __half22float2(kv1.b);
        float p0 = q4.x*k0a.x + q4.y*k0a.y + q4.z*k0b.x + q4.w*k0b.y;
        float p1 = q4.x*k1a.x + q4.y*k1a.y + q4.z*k1b.x + q4.w*k1b.y;
        p0 += __shfl_xor(p0, 1);  p1 += __shfl_xor(p1, 1);
        p0 += __shfl_xor(p0, 2);  p1 += __shfl_xor(p1, 2);
        p0 += __shfl_xor(p0, 4);  p1 += __shfl_xor(p1, 4);
        p0 += __shfl_xor(p0, 8);  p1 += __shfl_xor(p1, 8);
        const float eh0 = __expf(p0 * 0.125f);
        const float eh1 = __expf(p1 * 0.125f);
        const float2 v0a = __half22float2(kv0.c), v0b = __half22float2(kv0.d);
        const float2 v1a = __half22float2(kv1.c), v1b = __half22float2(kv1.d);
        ssum  += eh0 + eh1;
        acc.x += eh0*v0a.x + eh1*v1a.x;
        acc.y += eh0*v0a.y + eh1*v1a.y;
        acc.z += eh0*v0b.x + eh1*v1b.x;
        acc.w += eh0*v0b.y + eh1*v1b.y;
    }
    for (; e < e1; ++e) {
        const int s = colidx[e];
        const h8v kv = *(const h8v*)&KV[(size_t)s*512 + kvoff];
        const float2 ka = __half22float2(kv.a), kb = __half22float2(kv.b);
        float p = q4.x*ka.x + q4.y*ka.y + q4.z*kb.x + q4.w*kb.y;
        p += __shfl_xor(p, 1);
        p += __shfl_xor(p, 2);
        p += __shfl_xor(p, 4);
        p += __shfl_xor(p, 8);
        const float eh = __expf(p * 0.125f);
        const float2 va = __half22float2(kv.c), vb = __half22float2(kv.d);
        ssum  += eh;
        acc.x += eh*va.x; acc.y += eh*va.y; acc.z += eh*vb.x; acc.w += eh*vb.y;
    }
    const float inv = (ssum != 0.f) ? 1.f/ssum : 0.f;   // empty-segment guard
    acc.x *= inv; acc.y *= inv; acc.z *= inv; acc.w *= inv;

    // mean over heads: lanes {t, t+16, t+32, t+48} hold the same dims
    #pragma unroll
    for (int o = 16; o < 64; o <<= 1) {
        acc.x += __shfl_xor(acc.x, o); acc.y += __shfl_xor(acc.y, o);
        acc.z += __shfl_xor(acc.z, o); acc.w += __shfl_xor(acc.w, o);
    }
    const float4 sk4 = *(const float4*)&SKP[(size_t)n*64 + t*4];
    float4 val;
    val.x = acc.x*0.25f + sk4.x; val.y = acc.y*0.25f + sk4.y;
    val.z = acc.z*0.25f + sk4.z; val.w = acc.w*0.25f + sk4.w;

    // LayerNorm over 64 dims (each 16-lane group holds all 64)
    float m  = val.x + val.y + val.z + val.w;
    float m2 = val.x*val.x + val.y*val.y + val.z*val.z + val.w*val.w;
    #pragma unroll
    for (int o = 1; o < 16; o <<= 1) { m += __shfl_xor(m, o); m2 += __shfl_xor(m2, o); }
    m *= (1.f/64.f); m2 *= (1.f/64.f);
    const float rstd = rsqrtf(m2 - m*m + 1e-5f);
    const float4 g4 = *(const float4*)&g[t*4];
    const float4 b4 = *(const float4*)&b[t*4];
    float4 y;
    y.x = (val.x - m)*rstd*g4.x + b4.x;
    y.y = (val.y - m)*rstd*g4.y + b4.y;
    y.z = (val.z - m)*rstd*g4.z + b4.z;
    y.w = (val.w - m)*rstd*g4.w + b4.w;
    if (RELU) {
        y.x = fmaxf(y.x, 0.f); y.y = fmaxf(y.y, 0.f);
        y.z = fmaxf(y.z, 0.f); y.w = fmaxf(y.w, 0.f);
    }
    if (h == 0) *(float4*)&Hout[(size_t)n*64 + t*4] = y;
}

// ---------------- final 64->32 linear ----------------
__global__ __launch_bounds__(256) void final_gemm(
    const float* __restrict__ H, const float* __restrict__ Wf,
    const float* __restrict__ bf, float* __restrict__ out)
{
    __shared__ float sW[64][32];
    __shared__ float sH[8][64];
    const int tid = threadIdx.x;
    #pragma unroll
    for (int i = 0; i < 8; ++i) {
        int li = tid + 256*i;
        sW[li >> 5][li & 31] = Wf[li];
    }
    const int n0 = blockIdx.x * 8;
    #pragma unroll
    for (int i = 0; i < 2; ++i) {
        int li = tid + 256*i;
        int r = li >> 6, d = li & 63;
        int gn = n0 + r;
        sH[r][d] = (gn < NN) ? H[(size_t)gn*64 + d] : 0.f;
    }
    __syncthreads();
    const int o = tid & 31, nl = tid >> 5;
    const int gn = n0 + nl;
    if (gn >= NN) return;
    float acc = bf[o];
    #pragma unroll
    for (int dd = 0; dd < 64; ++dd) acc += sH[nl][dd] * sW[dd][o];
    out[(size_t)gn*32 + o] = acc;
}

extern "C" void kernel_launch(void* const* d_in, const int* in_sizes, int n_in,
                              void* d_out, int out_size, void* d_ws, size_t ws_size,
                              hipStream_t stream) {
    const float* x   = (const float*)d_in[0];
    const int*   ei  = (const int*)d_in[1];
    const int* srcA = ei;
    const int* dstA = ei + EE;
    const float *Wq1=(const float*)d_in[2],  *bq1=(const float*)d_in[3];
    const float *Wk1=(const float*)d_in[4],  *bk1=(const float*)d_in[5];
    const float *Wv1=(const float*)d_in[6],  *bv1=(const float*)d_in[7];
    const float *Ws1=(const float*)d_in[8],  *bs1=(const float*)d_in[9];
    const float *Wq2=(const float*)d_in[10], *bq2=(const float*)d_in[11];
    const float *Wk2=(const float*)d_in[12], *bk2=(const float*)d_in[13];
    const float *Wv2=(const float*)d_in[14], *bv2=(const float*)d_in[15];
    const float *Ws2=(const float*)d_in[16], *bs2=(const float*)d_in[17];
    const float *ln_g=(const float*)d_in[18],*ln_b=(const float*)d_in[19];
    const float *Wf=(const float*)d_in[20],  *bf=(const float*)d_in[21];
    float* out = (float*)d_out;

    float* ws = (float*)d_ws;
    size_t off = 0;
    float* Q    = ws + off; off += (size_t)NN*256;
    __half* KV  = (__half*)(ws + off); off += (size_t)NN*256;  // NN*512 halves
    float* SKP  = ws + off; off += (size_t)NN*64;
    float* H1   = ws + off; off += (size_t)NN*64;
    float* H2   = ws + off; off += (size_t)NN*64;
    int* deg    = (int*)(ws + off); off += NN;
    int* rowptr = (int*)(ws + off); off += NN + 1;
    int* cursor = (int*)(ws + off); off += NN;
    int* colidx = (int*)(ws + off); off += EE;

    const int rowTiles  = (NN + 127) / 128;      // 391
    const int gemmGrid  = 13 * rowTiles;         // 5083
    const int edgeBlocks = EE / 256;             // 3125
    const int nodeBlocks = NN / 4;               // 12500, 4 waves/block

    // ---- CSR build (dst-bucketed), used by both layers ----
    hipMemsetAsync(deg, 0, NN * sizeof(int), stream);
    hist_kernel<<<edgeBlocks, 256, 0, stream>>>(dstA, deg);
    scan_kernel<<<1, 1024, 0, stream>>>(deg, rowptr, cursor);
    scatter_kernel<<<edgeBlocks, 256, 0, stream>>>(srcA, dstA, cursor, colidx);

    // ---- layer 1 ----
    qkvs_gemm<128><<<gemmGrid, 256, 0, stream>>>(x, Wq1,bq1, Wk1,bk1, Wv1,bv1, Ws1,bs1,
                                                 Q, KV, SKP);
    node_attn<true><<<nodeBlocks, 256, 0, stream>>>(rowptr, colidx, Q, KV, SKP,
                                                    ln_g, ln_b, H1);

    // ---- layer 2 ----
    qkvs_gemm<64><<<gemmGrid, 256, 0, stream>>>(H1, Wq2,bq2, Wk2,bk2, Wv2,bv2, Ws2,bs2,
                                                Q, KV, SKP);
    node_attn<false><<<nodeBlocks, 256, 0, stream>>>(rowptr, colidx, Q, KV, SKP,
                                                     ln_g, ln_b, H2);

    // ---- final linear ----
    final_gemm<<<NN / 8, 256, 0, stream>>>(H2, Wf, bf, out);
}

// Round 9
// 688.699 us; speedup vs baseline: 1.3897x; 1.0791x over previous
//
#include <hip/hip_runtime.h>
#include <hip/hip_fp16.h>
#include <math.h>

#define NN 50000
#define EE 800000
#define HEADS 4
#define HIDD 64
#define OUTF 32

struct __align__(8)  h4v { __half2 a, b; };
struct __align__(16) h8v { __half2 a, b, c, d; };   // 4 K-halves + 4 V-halves

typedef __attribute__((ext_vector_type(8))) _Float16 f16x8;
typedef __attribute__((ext_vector_type(4))) _Float16 f16x4;
typedef __attribute__((ext_vector_type(4))) float    f32x4;

// ---------------- fused QKV+skip GEMM via f16 MFMA ----------------
// Grid: 13 * ceil(NN/64) blocks, bijectively remapped so the 13 weight tiles
// sharing one 64-row X strip run on the same XCD (round 8: FETCH 101.7->14.5MB).
// Block: 256 thr = 4 waves, 64x64 output tile. Full A(X) and B(W^T) tiles are
// staged in LDS as f16 ONCE (single barrier), then 16 mfma_f32_16x16x32_f16
// per wave. A/B fragments use the same k-indexing (k = 8*(lane>>4)+j), so any
// internal HW k-permutation cancels between operands; row/col = lane&15 and
// C/D mapping col=lane&15,row=(lane>>4)*4+reg are HW-verified (m89).
// tiles 0..3 -> Q (fp32), 4..7 -> K, 8..11 -> V (fp16 interleaved KV), 12 -> SKIP
template<int KDIM>
__global__ __launch_bounds__(256) void qkvs_gemm(
    const float* __restrict__ X,
    const float* __restrict__ Wq, const float* __restrict__ bq,
    const float* __restrict__ Wk, const float* __restrict__ bk,
    const float* __restrict__ Wv, const float* __restrict__ bv,
    const float* __restrict__ Ws, const float* __restrict__ bs,
    float* __restrict__ Q, __half* __restrict__ KV, float* __restrict__ SKP)
{
    constexpr int KP = KDIM + 8;          // f16 row stride: 272B / 144B, 16B-aligned
    __shared__ _Float16 Asm[64 * KP];
    __shared__ _Float16 Bsm[64 * KP];

    // bijective XCD remap (consecutive blockIdx -> round-robin XCD on MI355X)
    const int nwg = gridDim.x;
    const int i   = blockIdx.x;
    const int q8  = nwg >> 3, r8 = nwg & 7;
    const int xcd = i & 7, j = i >> 3;
    const int w   = (xcd < r8 ? xcd * (q8 + 1) : r8 * (q8 + 1) + (xcd - r8) * q8) + j;

    const int nt   = w % 13;              // weight tile
    const int row0 = (w / 13) * 64;

    const float* W; const float* bias; int mode, bcol, wstride;
    if (nt < 4)       { W = Wq; bias = bq; mode = 0; bcol = nt*64;     wstride = 256; }
    else if (nt < 8)  { W = Wk; bias = bk; mode = 1; bcol = (nt-4)*64; wstride = 256; }
    else if (nt < 12) { W = Wv; bias = bv; mode = 2; bcol = (nt-8)*64; wstride = 256; }
    else              { W = Ws; bias = bs; mode = 3; bcol = 0;         wstride = 64;  }

    const int tid = threadIdx.x;

    // ---- stage A (X tile, 64 x KDIM fp32 -> f16), coalesced float4 loads ----
    constexpr int AF4 = 64 * KDIM / 4;    // 2048 (K=128) / 1024 (K=64)
    #pragma unroll
    for (int li = tid; li < AF4; li += 256) {
        int r = li / (KDIM/4), c4 = li % (KDIM/4);
        int gr = row0 + r;
        float4 a4 = {0.f,0.f,0.f,0.f};
        if (gr < NN) a4 = *(const float4*)&X[(size_t)gr*KDIM + c4*4];
        f16x4 hv = { (_Float16)a4.x, (_Float16)a4.y, (_Float16)a4.z, (_Float16)a4.w };
        *(f16x4*)&Asm[r*KP + c4*4] = hv;
    }
    // ---- stage B transposed (W [k][col] -> Bsm[col][k] f16) ----
    constexpr int BF4 = KDIM * 16;        // KDIM x 64 fp32 in float4s
    #pragma unroll
    for (int li = tid; li < BF4; li += 256) {
        int k = li >> 4, c4 = li & 15;
        float4 wv4 = *(const float4*)&W[(size_t)k*wstride + bcol + c4*4];
        Bsm[(c4*4+0)*KP + k] = (_Float16)wv4.x;
        Bsm[(c4*4+1)*KP + k] = (_Float16)wv4.y;
        Bsm[(c4*4+2)*KP + k] = (_Float16)wv4.z;
        Bsm[(c4*4+3)*KP + k] = (_Float16)wv4.w;
    }
    __syncthreads();

    // ---- MFMA compute: wave wv owns rows wv*16..+15, 4 col-tiles of 16 ----
    const int lane = tid & 63, wvi = tid >> 6;
    const int lr = lane & 15, lg = lane >> 4;
    const int arow = wvi*16 + lr;

    f32x4 acc[4];
    #pragma unroll
    for (int ci = 0; ci < 4; ++ci) acc[ci] = (f32x4){0.f,0.f,0.f,0.f};

    #pragma unroll
    for (int k0 = 0; k0 < KDIM; k0 += 32) {
        f16x8 af = *(const f16x8*)&Asm[arow*KP + k0 + lg*8];
        #pragma unroll
        for (int ci = 0; ci < 4; ++ci) {
            f16x8 bf = *(const f16x8*)&Bsm[(ci*16 + lr)*KP + k0 + lg*8];
            acc[ci] = __builtin_amdgcn_mfma_f32_16x16x32_f16(af, bf, acc[ci], 0, 0, 0);
        }
    }

    // ---- epilogue: bias + store (D: row=(lane>>4)*4+i, col=lane&15) ----
    #pragma unroll
    for (int ci = 0; ci < 4; ++ci) {
        const int col = ci*16 + lr;              // within 64-col tile
        const float bia = bias[bcol + col];
        #pragma unroll
        for (int ii = 0; ii < 4; ++ii) {
            int gr = row0 + wvi*16 + lg*4 + ii;
            if (gr >= NN) continue;
            float o = acc[ci][ii] + bia;
            if (mode == 0) {
                Q[(size_t)gr*256 + bcol + col] = o;
            } else if (mode == 3) {
                SKP[(size_t)gr*64 + col] = o;
            } else {
                int h = bcol >> 6;               // head index (K/V tiles are 64-aligned)
                int d = col;                     // 0..63 within head
                size_t idx = (size_t)gr*512 + h*128 + ((d>>2)<<3) + (d&3)
                             + (mode == 2 ? 4 : 0);
                KV[idx] = __float2half(o);
            }
        }
    }
}

// ---------------- CSR build (dst-bucketed), reused by both layers ----------------
__global__ __launch_bounds__(256) void hist_kernel(const int* __restrict__ dstA,
                                                   int* __restrict__ deg)
{
    int e = blockIdx.x * 256 + threadIdx.x;   // EE divisible by 256
    atomicAdd(&deg[dstA[e]], 1);
}

__global__ __launch_bounds__(1024) void scan_kernel(const int* __restrict__ deg,
                                                    int* __restrict__ rowptr,
                                                    int* __restrict__ cursor)
{
    __shared__ int sdata[1024];
    __shared__ int soff;
    const int tid = threadIdx.x;
    if (tid == 0) soff = 0;
    __syncthreads();
    for (int base = 0; base < NN; base += 1024) {
        int v = (base + tid < NN) ? deg[base + tid] : 0;
        sdata[tid] = v;
        __syncthreads();
        #pragma unroll
        for (int off = 1; off < 1024; off <<= 1) {
            int t = (tid >= off) ? sdata[tid - off] : 0;
            __syncthreads();
            sdata[tid] += t;
            __syncthreads();
        }
        int excl = sdata[tid] - v;
        if (base + tid < NN) {
            rowptr[base + tid] = soff + excl;
            cursor[base + tid] = soff + excl;
        }
        int total = sdata[1023];
        __syncthreads();
        if (tid == 0) soff += total;
        __syncthreads();
    }
    if (tid == 0) rowptr[NN] = EE;
}

__global__ __launch_bounds__(256) void scatter_kernel(const int* __restrict__ srcA,
                                                      const int* __restrict__ dstA,
                                                      int* __restrict__ cursor,
                                                      int* __restrict__ colidx)
{
    int e = blockIdx.x * 256 + threadIdx.x;
    int p = atomicAdd(&cursor[dstA[e]], 1);
    colidx[p] = srcA[e];
}

// ---------------- fused node-centric attention + head-mean + skip + LN ----------------
// one wave per node; lane: h = lane>>4 (head), t = lane&15.
// ONE 16B load per edge per lane (K-chunk + V-chunk interleaved).
template<bool RELU>
__global__ __launch_bounds__(256) void node_attn(
    const int* __restrict__ rowptr, const int* __restrict__ colidx,
    const float* __restrict__ Q, const __half* __restrict__ KV,
    const float* __restrict__ SKP,
    const float* __restrict__ g, const float* __restrict__ b,
    float* __restrict__ Hout)
{
    int n = (blockIdx.x * blockDim.x + threadIdx.x) >> 6;
    if (n >= NN) return;
    const int lane = threadIdx.x & 63;
    const int h = lane >> 4, t = lane & 15;
    const int kvoff = h*128 + t*8;

    const float4 q4 = *(const float4*)&Q[(size_t)n*256 + h*64 + t*4];

    float4 acc = {0.f,0.f,0.f,0.f};
    float ssum = 0.f;
    const int e0 = rowptr[n], e1 = rowptr[n+1];
    int e = e0;
    for (; e + 2 <= e1; e += 2) {
        const int s0 = colidx[e], s1 = colidx[e+1];
        const h8v kv0 = *(const h8v*)&KV[(size_t)s0*512 + kvoff];
        const h8v kv1 = *(const h8v*)&KV[(size_t)s1*512 + kvoff];
        const float2 k0a = __half22float2(kv0.a), k0b = __half22float2(kv0.b);
        const float2 k1a = __half22float2(kv1.a), k1b = __half22float2(kv1.b);
        float p0 = q4.x*k0a.x + q4.y*k0a.y + q4.z*k0b.x + q4.w*k0b.y;
        float p1 = q4.x*k1a.x + q4.y*k1a.y + q4.z*k1b.x + q4.w*k1b.y;
        p0 += __shfl_xor(p0, 1);  p1 += __shfl_xor(p1, 1);
        p0 += __shfl_xor(p0, 2);  p1 += __shfl_xor(p1, 2);
        p0 += __shfl_xor(p0, 4);  p1 += __shfl_xor(p1, 4);
        p0 += __shfl_xor(p0, 8);  p1 += __shfl_xor(p1, 8);
        const float eh0 = __expf(p0 * 0.125f);
        const float eh1 = __expf(p1 * 0.125f);
        const float2 v0a = __half22float2(kv0.c), v0b = __half22float2(kv0.d);
        const float2 v1a = __half22float2(kv1.c), v1b = __half22float2(kv1.d);
        ssum  += eh0 + eh1;
        acc.x += eh0*v0a.x + eh1*v1a.x;
        acc.y += eh0*v0a.y + eh1*v1a.y;
        acc.z += eh0*v0b.x + eh1*v1b.x;
        acc.w += eh0*v0b.y + eh1*v1b.y;
    }
    for (; e < e1; ++e) {
        const int s = colidx[e];
        const h8v kv = *(const h8v*)&KV[(size_t)s*512 + kvoff];
        const float2 ka = __half22float2(kv.a), kb = __half22float2(kv.b);
        float p = q4.x*ka.x + q4.y*ka.y + q4.z*kb.x + q4.w*kb.y;
        p += __shfl_xor(p, 1);
        p += __shfl_xor(p, 2);
        p += __shfl_xor(p, 4);
        p += __shfl_xor(p, 8);
        const float eh = __expf(p * 0.125f);
        const float2 va = __half22float2(kv.c), vb = __half22float2(kv.d);
        ssum  += eh;
        acc.x += eh*va.x; acc.y += eh*va.y; acc.z += eh*vb.x; acc.w += eh*vb.y;
    }
    const float inv = (ssum != 0.f) ? 1.f/ssum : 0.f;   // empty-segment guard
    acc.x *= inv; acc.y *= inv; acc.z *= inv; acc.w *= inv;

    // mean over heads: lanes {t, t+16, t+32, t+48} hold the same dims
    #pragma unroll
    for (int o = 16; o < 64; o <<= 1) {
        acc.x += __shfl_xor(acc.x, o); acc.y += __shfl_xor(acc.y, o);
        acc.z += __shfl_xor(acc.z, o); acc.w += __shfl_xor(acc.w, o);
    }
    const float4 sk4 = *(const float4*)&SKP[(size_t)n*64 + t*4];
    float4 val;
    val.x = acc.x*0.25f + sk4.x; val.y = acc.y*0.25f + sk4.y;
    val.z = acc.z*0.25f + sk4.z; val.w = acc.w*0.25f + sk4.w;

    // LayerNorm over 64 dims (each 16-lane group holds all 64)
    float m  = val.x + val.y + val.z + val.w;
    float m2 = val.x*val.x + val.y*val.y + val.z*val.z + val.w*val.w;
    #pragma unroll
    for (int o = 1; o < 16; o <<= 1) { m += __shfl_xor(m, o); m2 += __shfl_xor(m2, o); }
    m *= (1.f/64.f); m2 *= (1.f/64.f);
    const float rstd = rsqrtf(m2 - m*m + 1e-5f);
    const float4 g4 = *(const float4*)&g[t*4];
    const float4 b4 = *(const float4*)&b[t*4];
    float4 y;
    y.x = (val.x - m)*rstd*g4.x + b4.x;
    y.y = (val.y - m)*rstd*g4.y + b4.y;
    y.z = (val.z - m)*rstd*g4.z + b4.z;
    y.w = (val.w - m)*rstd*g4.w + b4.w;
    if (RELU) {
        y.x = fmaxf(y.x, 0.f); y.y = fmaxf(y.y, 0.f);
        y.z = fmaxf(y.z, 0.f); y.w = fmaxf(y.w, 0.f);
    }
    if (h == 0) *(float4*)&Hout[(size_t)n*64 + t*4] = y;
}

// ---------------- final 64->32 linear ----------------
__global__ __launch_bounds__(256) void final_gemm(
    const float* __restrict__ H, const float* __restrict__ Wf,
    const float* __restrict__ bf, float* __restrict__ out)
{
    __shared__ float sW[64][32];
    __shared__ float sH[8][64];
    const int tid = threadIdx.x;
    #pragma unroll
    for (int i = 0; i < 8; ++i) {
        int li = tid + 256*i;
        sW[li >> 5][li & 31] = Wf[li];
    }
    const int n0 = blockIdx.x * 8;
    #pragma unroll
    for (int i = 0; i < 2; ++i) {
        int li = tid + 256*i;
        int r = li >> 6, d = li & 63;
        int gn = n0 + r;
        sH[r][d] = (gn < NN) ? H[(size_t)gn*64 + d] : 0.f;
    }
    __syncthreads();
    const int o = tid & 31, nl = tid >> 5;
    const int gn = n0 + nl;
    if (gn >= NN) return;
    float acc = bf[o];
    #pragma unroll
    for (int dd = 0; dd < 64; ++dd) acc += sH[nl][dd] * sW[dd][o];
    out[(size_t)gn*32 + o] = acc;
}

extern "C" void kernel_launch(void* const* d_in, const int* in_sizes, int n_in,
                              void* d_out, int out_size, void* d_ws, size_t ws_size,
                              hipStream_t stream) {
    const float* x   = (const float*)d_in[0];
    const int*   ei  = (const int*)d_in[1];
    const int* srcA = ei;
    const int* dstA = ei + EE;
    const float *Wq1=(const float*)d_in[2],  *bq1=(const float*)d_in[3];
    const float *Wk1=(const float*)d_in[4],  *bk1=(const float*)d_in[5];
    const float *Wv1=(const float*)d_in[6],  *bv1=(const float*)d_in[7];
    const float *Ws1=(const float*)d_in[8],  *bs1=(const float*)d_in[9];
    const float *Wq2=(const float*)d_in[10], *bq2=(const float*)d_in[11];
    const float *Wk2=(const float*)d_in[12], *bk2=(const float*)d_in[13];
    const float *Wv2=(const float*)d_in[14], *bv2=(const float*)d_in[15];
    const float *Ws2=(const float*)d_in[16], *bs2=(const float*)d_in[17];
    const float *ln_g=(const float*)d_in[18],*ln_b=(const float*)d_in[19];
    const float *Wf=(const float*)d_in[20],  *bf=(const float*)d_in[21];
    float* out = (float*)d_out;

    float* ws = (float*)d_ws;
    size_t off = 0;
    float* Q    = ws + off; off += (size_t)NN*256;
    __half* KV  = (__half*)(ws + off); off += (size_t)NN*256;  // NN*512 halves
    float* SKP  = ws + off; off += (size_t)NN*64;
    float* H1   = ws + off; off += (size_t)NN*64;
    float* H2   = ws + off; off += (size_t)NN*64;
    int* deg    = (int*)(ws + off); off += NN;
    int* rowptr = (int*)(ws + off); off += NN + 1;
    int* cursor = (int*)(ws + off); off += NN;
    int* colidx = (int*)(ws + off); off += EE;

    const int rowTiles  = (NN + 63) / 64;        // 782
    const int gemmGrid  = 13 * rowTiles;         // 10166
    const int edgeBlocks = EE / 256;             // 3125
    const int nodeBlocks = NN / 4;               // 12500, 4 waves/block

    // ---- CSR build (dst-bucketed), used by both layers ----
    hipMemsetAsync(deg, 0, NN * sizeof(int), stream);
    hist_kernel<<<edgeBlocks, 256, 0, stream>>>(dstA, deg);
    scan_kernel<<<1, 1024, 0, stream>>>(deg, rowptr, cursor);
    scatter_kernel<<<edgeBlocks, 256, 0, stream>>>(srcA, dstA, cursor, colidx);

    // ---- layer 1 ----
    qkvs_gemm<128><<<gemmGrid, 256, 0, stream>>>(x, Wq1,bq1, Wk1,bk1, Wv1,bv1, Ws1,bs1,
                                                 Q, KV, SKP);
    node_attn<true><<<nodeBlocks, 256, 0, stream>>>(rowptr, colidx, Q, KV, SKP,
                                                    ln_g, ln_b, H1);

    // ---- layer 2 ----
    qkvs_gemm<64><<<gemmGrid, 256, 0, stream>>>(H1, Wq2,bq2, Wk2,bk2, Wv2,bv2, Ws2,bs2,
                                                Q, KV, SKP);
    node_attn<false><<<nodeBlocks, 256, 0, stream>>>(rowptr, colidx, Q, KV, SKP,
                                                     ln_g, ln_b, H2);

    // ---- final linear ----
    final_gemm<<<NN / 8, 256, 0, stream>>>(H2, Wf, bf, out);
}